// Round 6
// baseline (390.841 us; speedup 1.0000x reference)
//
#include <hip/hip_runtime.h>

#define TT 4
#define NN 50000
#define DH 64
#define EE 800000
#define BN_EPS 1e-5f
#define G1 64           // prep blocks per t
#define G2 128          // blocks for stats_avg
#define RANK_BLOCKS 3125 // EE/256 exact

typedef __attribute__((ext_vector_type(8))) short short8;
typedef __attribute__((ext_vector_type(4))) float floatx4;

// ---------------- ws layout (byte offsets) ----------------
#define WS_DEG      0          // 50000 i   (memset [0,200000))
#define WS_ROWSTART 200704     // 50001 i
#define WS_PX       403456     // [4][G1][64] f = 65536 B
#define WS_PX2      468992     // 65536 B
#define WS_PA       534528     // [G2][64] f = 32768 B
#define WS_PA2      567296     // 32768 B
#define WS_W1EFF    600064     // 12288 bf16 = 24576 B
#define WS_B1EFF    624640     // 64 f
#define WS_PACKED   1048576    // 800000 int2 = 6.4 MB -> 7448576
#define WS_XB       8388608    // 200000*64 bf16 = 25.6 MB -> 33988608
#define WS_AVGB     34078720   // 200000*64 bf16 = 25.6 MB -> ends 59678720
#define WS_RANK     34078720   // 800000 i (aliases avgb; dead before k_agg writes)

__device__ __forceinline__ unsigned short f2b(float f) {
    unsigned int u = __float_as_uint(f);
    unsigned int r = (u + 0x7FFFu + ((u >> 16) & 1u)) >> 16;
    return (unsigned short)r;
}
__device__ __forceinline__ float b2f(unsigned short u) {
    return __uint_as_float((unsigned int)u << 16);
}

// Fused: blocks [0,RANK_BLOCKS) do the rank/deg atomics (latency-bound);
// blocks [RANK_BLOCKS, +256) do x->bf16 + per-(t,c) stats (BW-bound).
__global__ __launch_bounds__(256) void k_prep_rank(
    const float* __restrict__ x, unsigned short* __restrict__ xb,
    float* __restrict__ PX, float* __restrict__ PX2,
    const int* __restrict__ dst, int* __restrict__ deg, int* __restrict__ rank) {
    __shared__ float ls[256 * 4], ls2[256 * 4];
    int b = blockIdx.x;
    int tid = threadIdx.x;
    if (b < RANK_BLOCKS) {
        int e = b * 256 + tid;                 // EE = RANK_BLOCKS*256 exact
        rank[e] = atomicAdd(&deg[dst[e]], 1);
        return;
    }
    int pb = b - RANK_BLOCKS;                  // 0..255
    int t = pb >> 6;
    int g = (pb & 63) * 256 + tid;
    const float4* xt = (const float4*)(x + (size_t)t * NN * 64);
    unsigned short* xbt = xb + (size_t)t * NN * 64;
    float s[4] = {0.f, 0.f, 0.f, 0.f}, s2[4] = {0.f, 0.f, 0.f, 0.f};
    for (int v = g; v < NN * 16; v += G1 * 256) {     // stride mult of 16 -> c-group fixed
        float4 d = xt[v];
        ushort4 o;
        o.x = f2b(d.x); o.y = f2b(d.y); o.z = f2b(d.z); o.w = f2b(d.w);
        *(ushort4*)(xbt + (size_t)v * 4) = o;
        s[0] += d.x; s2[0] += d.x * d.x;
        s[1] += d.y; s2[1] += d.y * d.y;
        s[2] += d.z; s2[2] += d.z * d.z;
        s[3] += d.w; s2[3] += d.w * d.w;
    }
#pragma unroll
    for (int j = 0; j < 4; ++j) { ls[tid * 4 + j] = s[j]; ls2[tid * 4 + j] = s2[j]; }
    __syncthreads();
    if (tid < 64) {
        int g16 = tid >> 2, comp = tid & 3;
        float rs = 0.f, rs2 = 0.f;
#pragma unroll
        for (int k = 0; k < 16; ++k) {
            int j = g16 + 16 * k;
            rs += ls[j * 4 + comp]; rs2 += ls2[j * 4 + comp];
        }
        int slot = (t * G1 + (pb & 63)) * 64 + tid;
        PX[slot] = rs; PX2[slot] = rs2;
    }
}

// single-block exclusive scan of deg -> row_start (wave shuffle scan, 2 syncs/tile)
__global__ __launch_bounds__(1024) void k_scan(const int* __restrict__ deg,
                                              int* __restrict__ row_start) {
    __shared__ int wtot[16], wpre[16];
    __shared__ int base_s;
    int tid = threadIdx.x;
    int lane = tid & 63;
    int w = tid >> 6;
    if (tid == 0) base_s = 0;
    __syncthreads();
    for (int tile = 0; tile < 49; ++tile) {
        int i = tile * 1024 + tid;
        int v = (i < NN) ? deg[i] : 0;
        int incl = v;
#pragma unroll
        for (int off = 1; off < 64; off <<= 1) {
            int tv = __shfl_up(incl, off, 64);
            if (lane >= off) incl += tv;
        }
        if (lane == 63) wtot[w] = incl;
        __syncthreads();
        if (tid == 0) {
            int run = 0;
#pragma unroll
            for (int k = 0; k < 16; ++k) { wpre[k] = run; run += wtot[k]; }
            wtot[0] = run;                     // tile total
        }
        __syncthreads();
        int excl = base_s + wpre[w] + incl - v;
        if (i < NN) row_start[i] = excl;
        if (i == NN - 1) row_start[NN] = excl + v;
        __syncthreads();                       // all consumed base_s/wpre
        if (tid == 0) base_s += wtot[0];
        __syncthreads();                       // before next tile's wtot writes
    }
}

// atomic-free CSR fill: position = row_start[dst] + rank
__global__ void k_fill2(const int* __restrict__ src, const int* __restrict__ dst,
                        const float* __restrict__ ew, const int* __restrict__ rank,
                        const int* __restrict__ row_start, int2* __restrict__ packed) {
    int e = blockIdx.x * 256 + threadIdx.x;
    if (e < EE) {
        int p = row_start[dst[e]] + rank[e];
        packed[p] = make_int2(src[e], __float_as_int(ew[e]));
    }
}

// one wave per node; lane l -> (t = l>>4, channels 4*(l&15)..+3), ushort4 gathers.
// Edge loop is wave-uniform & scalarized (s_loads); 4-edge unroll for MLP.
__global__ __launch_bounds__(256) void k_agg(
    const unsigned short* __restrict__ xb, const int2* __restrict__ packed,
    const int* __restrict__ row_start, unsigned short* __restrict__ avgb) {
    int wv = __builtin_amdgcn_readfirstlane(threadIdx.x >> 6);
    int n = blockIdx.x * 4 + wv;
    int l = threadIdx.x & 63;
    int t = l >> 4;
    int cg = (l & 15) * 4;
    const unsigned short* xt = xb + (size_t)t * NN * 64 + cg;
    int rs = row_start[n], re = row_start[n + 1];
    float a0 = 0.f, a1 = 0.f, a2 = 0.f, a3 = 0.f, wsum = 0.f;
    int e = rs;
    for (; e + 4 <= re; e += 4) {
        int2 p0 = packed[e], p1 = packed[e + 1], p2 = packed[e + 2], p3 = packed[e + 3];
        ushort4 v0 = *(const ushort4*)(xt + (size_t)p0.x * 64);
        ushort4 v1 = *(const ushort4*)(xt + (size_t)p1.x * 64);
        ushort4 v2 = *(const ushort4*)(xt + (size_t)p2.x * 64);
        ushort4 v3 = *(const ushort4*)(xt + (size_t)p3.x * 64);
        float w0 = __int_as_float(p0.y), w1 = __int_as_float(p1.y);
        float w2 = __int_as_float(p2.y), w3 = __int_as_float(p3.y);
        wsum += (w0 + w1) + (w2 + w3);
        a0 = fmaf(w0, b2f(v0.x), a0); a1 = fmaf(w0, b2f(v0.y), a1);
        a2 = fmaf(w0, b2f(v0.z), a2); a3 = fmaf(w0, b2f(v0.w), a3);
        a0 = fmaf(w1, b2f(v1.x), a0); a1 = fmaf(w1, b2f(v1.y), a1);
        a2 = fmaf(w1, b2f(v1.z), a2); a3 = fmaf(w1, b2f(v1.w), a3);
        a0 = fmaf(w2, b2f(v2.x), a0); a1 = fmaf(w2, b2f(v2.y), a1);
        a2 = fmaf(w2, b2f(v2.z), a2); a3 = fmaf(w2, b2f(v2.w), a3);
        a0 = fmaf(w3, b2f(v3.x), a0); a1 = fmaf(w3, b2f(v3.y), a1);
        a2 = fmaf(w3, b2f(v3.z), a2); a3 = fmaf(w3, b2f(v3.w), a3);
    }
    for (; e < re; ++e) {
        int2 p0 = packed[e];
        float w0 = __int_as_float(p0.y);
        ushort4 v0 = *(const ushort4*)(xt + (size_t)p0.x * 64);
        wsum += w0;
        a0 = fmaf(w0, b2f(v0.x), a0); a1 = fmaf(w0, b2f(v0.y), a1);
        a2 = fmaf(w0, b2f(v0.z), a2); a3 = fmaf(w0, b2f(v0.w), a3);
    }
    float rz = (wsum == 0.f) ? 1.f : (1.f / wsum);
    ushort4 o;
    o.x = f2b(a0 * rz); o.y = f2b(a1 * rz); o.z = f2b(a2 * rz); o.w = f2b(a3 * rz);
    *(ushort4*)(avgb + (size_t)t * NN * 64 + (size_t)n * 64 + cg) = o;
}

// per-c sum/sumsq partials of avg (bf16), short8 loads, no atomics
__global__ __launch_bounds__(256) void k_stats_avg(
    const unsigned short* __restrict__ avgb, float* __restrict__ PA,
    float* __restrict__ PA2) {
    int tid = threadIdx.x;
    int g = blockIdx.x * 256 + tid;
    const short8* av = (const short8*)avgb;
    float s[8], s2[8];
#pragma unroll
    for (int j = 0; j < 8; ++j) { s[j] = 0.f; s2[j] = 0.f; }
    for (int v = g; v < TT * NN * 8; v += G2 * 256) {
        short8 d = av[v];
#pragma unroll
        for (int j = 0; j < 8; ++j) {
            float f = b2f((unsigned short)d[j]);
            s[j] += f; s2[j] += f * f;
        }
    }
    __shared__ float ls[256 * 8], ls2[256 * 8];
#pragma unroll
    for (int j = 0; j < 8; ++j) { ls[tid * 8 + j] = s[j]; ls2[tid * 8 + j] = s2[j]; }
    __syncthreads();
    if (tid < 64) {
        int g8 = tid >> 3, comp = tid & 7;
        float rs = 0.f, rs2 = 0.f;
#pragma unroll
        for (int k = 0; k < 32; ++k) {
            int j = g8 + 8 * k;
            rs += ls[j * 8 + comp]; rs2 += ls2[j * 8 + comp];
        }
        PA[blockIdx.x * 64 + tid] = rs;
        PA2[blockIdx.x * 64 + tid] = rs2;
    }
}

// stage-2 reduce + BN fold into bf16 W1eff / fp32 b1eff
__global__ void k_fold(const float* __restrict__ W1, const float* __restrict__ b1,
                       const float* __restrict__ gamma, const float* __restrict__ beta,
                       const float* __restrict__ PX, const float* __restrict__ PX2,
                       const float* __restrict__ PA, const float* __restrict__ PA2,
                       unsigned short* __restrict__ W1eff, float* __restrict__ b1eff) {
    __shared__ float gS[192], hS[192];
    int c = threadIdx.x;                        // 192 threads
    const float inv = 1.0f / (float)(TT * NN);
    if (c < 192) {
        float s = 0.f, s2 = 0.f;
        if (c < 64) {
            for (int i = 0; i < TT * G1; ++i) { s += PX[i * 64 + c]; s2 += PX2[i * 64 + c]; }
        } else if (c < 128) {
            int cc = c - 64;                    // prev: t=0..2 only
            for (int i = 0; i < (TT - 1) * G1; ++i) { s += PX[i * 64 + cc]; s2 += PX2[i * 64 + cc]; }
        } else {
            int cc = c - 128;
            for (int i = 0; i < G2; ++i) { s += PA[i * 64 + cc]; s2 += PA2[i * 64 + cc]; }
        }
        float mu = s * inv, ex2 = s2 * inv;
        float var = ex2 - mu * mu;
        float g = gamma[c] / sqrtf(var + BN_EPS);
        gS[c] = g;
        hS[c] = beta[c] - mu * g;
    }
    __syncthreads();
    for (int i = threadIdx.x; i < 64 * 192; i += blockDim.x) {
        int cc = i % 192;
        W1eff[i] = f2b(W1[i] * gS[cc]);
    }
    if (threadIdx.x < 64) {
        int o = threadIdx.x;
        float acc = b1[o];
        for (int cc = 0; cc < 192; ++cc) acc += hS[cc] * W1[o * 192 + cc];
        b1eff[o] = acc;
    }
}

// MFMA GEMM: block = 4 waves, wave = 16 rows x 64 outs (4 col-tiles), K=192
__global__ __launch_bounds__(256) void k_main(
    const unsigned short* __restrict__ xb, const unsigned short* __restrict__ avgb,
    const unsigned short* __restrict__ Wb, const float* __restrict__ bias,
    float* __restrict__ out) {
    int wave = threadIdx.x >> 6;
    int lane = threadIdx.x & 63;
    int r0 = blockIdx.x * 64 + wave * 16;
    int m = lane & 15;
    int q = lane >> 4;

    const unsigned short* xrow = xb   + (size_t)(r0 + m) * 64 + q * 8;
    const unsigned short* prow = xb   + (size_t)(r0 - NN + m) * 64 + q * 8;
    const unsigned short* arow = avgb + (size_t)(r0 + m) * 64 + q * 8;
    bool has_prev = (r0 >= NN);

    floatx4 acc[4];
#pragma unroll
    for (int ct = 0; ct < 4; ++ct) acc[ct] = (floatx4){0.f, 0.f, 0.f, 0.f};

    const short8 zf = (short8){0, 0, 0, 0, 0, 0, 0, 0};

#pragma unroll
    for (int kc = 0; kc < 6; ++kc) {
        short8 a;
        if (kc < 2) {
            a = *(const short8*)(xrow + kc * 32);
        } else if (kc < 4) {
            a = has_prev ? *(const short8*)(prow + (kc - 2) * 32) : zf;
        } else {
            a = *(const short8*)(arow + (kc - 4) * 32);
        }
#pragma unroll
        for (int ct = 0; ct < 4; ++ct) {
            short8 b = *(const short8*)(Wb + (size_t)(ct * 16 + m) * 192 + kc * 32 + q * 8);
            acc[ct] = __builtin_amdgcn_mfma_f32_16x16x32_bf16(a, b, acc[ct], 0, 0, 0);
        }
    }

#pragma unroll
    for (int ct = 0; ct < 4; ++ct) {
        float bv = bias[ct * 16 + m];
#pragma unroll
        for (int i = 0; i < 4; ++i) {
            int row = q * 4 + i;
            out[(size_t)(r0 + row) * 64 + ct * 16 + m] = fmaxf(acc[ct][i] + bv, 0.f);
        }
    }
}

extern "C" void kernel_launch(void* const* d_in, const int* in_sizes, int n_in,
                              void* d_out, int out_size, void* d_ws, size_t ws_size,
                              hipStream_t stream) {
    const float* x     = (const float*)d_in[0];
    const float* ew    = (const float*)d_in[1];
    const float* W1    = (const float*)d_in[2];
    const float* b1    = (const float*)d_in[3];
    const float* gamma = (const float*)d_in[4];
    const float* beta  = (const float*)d_in[5];
    const int*   src   = (const int*)d_in[6];
    const int*   dst   = (const int*)d_in[7];
    float* out = (float*)d_out;
    char*  ws  = (char*)d_ws;

    int*   deg      = (int*)(ws + WS_DEG);
    int*   row_start= (int*)(ws + WS_ROWSTART);
    float* PX       = (float*)(ws + WS_PX);
    float* PX2      = (float*)(ws + WS_PX2);
    float* PA       = (float*)(ws + WS_PA);
    float* PA2      = (float*)(ws + WS_PA2);
    unsigned short* W1eff = (unsigned short*)(ws + WS_W1EFF);
    float* b1eff    = (float*)(ws + WS_B1EFF);
    int2*  packed   = (int2*)(ws + WS_PACKED);
    unsigned short* xb   = (unsigned short*)(ws + WS_XB);
    unsigned short* avgb = (unsigned short*)(ws + WS_AVGB);
    int*   rank     = (int*)(ws + WS_RANK);

    hipMemsetAsync(ws, 0, 200000, stream);          // deg only

    k_prep_rank<<<RANK_BLOCKS + 256, 256, 0, stream>>>(x, xb, PX, PX2, dst, deg, rank);

    k_scan<<<1, 1024, 0, stream>>>(deg, row_start);

    k_fill2<<<(EE + 255) / 256, 256, 0, stream>>>(src, dst, ew, rank, row_start, packed);

    k_agg<<<NN / 4, 256, 0, stream>>>(xb, packed, row_start, avgb);

    k_stats_avg<<<G2, 256, 0, stream>>>(avgb, PA, PA2);

    k_fold<<<1, 192, 0, stream>>>(W1, b1, gamma, beta, PX, PX2, PA, PA2, W1eff, b1eff);

    k_main<<<(TT * NN) / 64, 256, 0, stream>>>(xb, avgb, W1eff, b1eff, out);
}

// Round 7
// 352.891 us; speedup vs baseline: 1.1075x; 1.1075x over previous
//
#include <hip/hip_runtime.h>

#define TT 4
#define NN 50000
#define DH 64
#define EE 800000
#define BN_EPS 1e-5f
#define NB 196          // ceil(NN/256)
#define G1 64           // prep blocks per t
#define G2 128          // blocks for stats_avg

typedef __attribute__((ext_vector_type(8))) short short8;
typedef __attribute__((ext_vector_type(4))) float floatx4;

// ---------------- ws layout (byte offsets) ----------------
#define WS_DEG      0          // 50000 i   (memset [0,200000))
#define WS_ROWSTART 200704     // 50001 i
#define WS_BSUM     401408     // 196 i
#define WS_BSCAN    402432     // 196 i
#define WS_PX       403456     // [4][G1][64] f = 65536 B
#define WS_PX2      468992     // 65536 B
#define WS_PA       534528     // [G2][64] f = 32768 B
#define WS_PA2      567296     // 32768 B
#define WS_W1EFF    600064     // 12288 bf16 = 24576 B
#define WS_B1EFF    624640     // 64 f
#define WS_PACKED   1048576    // 800000 int2 = 6.4 MB -> 7448576
#define WS_XB       8388608    // 200000*64 bf16 = 25.6 MB -> 33988608
#define WS_AVGB     34078720   // 200000*64 bf16 = 25.6 MB -> ends 59678720
#define WS_RANK     34078720   // 800000 i (aliases avgb; dead before k_agg writes)

__device__ __forceinline__ unsigned short f2b(float f) {
    unsigned int u = __float_as_uint(f);
    unsigned int r = (u + 0x7FFFu + ((u >> 16) & 1u)) >> 16;
    return (unsigned short)r;
}
__device__ __forceinline__ float b2f(unsigned short u) {
    return __uint_as_float((unsigned int)u << 16);
}

// x(fp32) -> xb(bf16) + per-(t,c) sum/sumsq partials (pure streaming, no atomics)
__global__ __launch_bounds__(256) void k_prep_stats(
    const float* __restrict__ x, unsigned short* __restrict__ xb,
    float* __restrict__ PX, float* __restrict__ PX2) {
    int t = blockIdx.y;
    int tid = threadIdx.x;
    int g = blockIdx.x * 256 + tid;
    const float4* xt = (const float4*)(x + (size_t)t * NN * 64);
    unsigned short* xbt = xb + (size_t)t * NN * 64;
    float s[4] = {0.f, 0.f, 0.f, 0.f}, s2[4] = {0.f, 0.f, 0.f, 0.f};
    for (int v = g; v < NN * 16; v += G1 * 256) {     // stride mult of 16 -> c-group fixed
        float4 d = xt[v];
        ushort4 o;
        o.x = f2b(d.x); o.y = f2b(d.y); o.z = f2b(d.z); o.w = f2b(d.w);
        *(ushort4*)(xbt + (size_t)v * 4) = o;
        s[0] += d.x; s2[0] += d.x * d.x;
        s[1] += d.y; s2[1] += d.y * d.y;
        s[2] += d.z; s2[2] += d.z * d.z;
        s[3] += d.w; s2[3] += d.w * d.w;
    }
    __shared__ float ls[256 * 4], ls2[256 * 4];
#pragma unroll
    for (int j = 0; j < 4; ++j) { ls[tid * 4 + j] = s[j]; ls2[tid * 4 + j] = s2[j]; }
    __syncthreads();
    if (tid < 64) {
        int g16 = tid >> 2, comp = tid & 3;
        float rs = 0.f, rs2 = 0.f;
#pragma unroll
        for (int k = 0; k < 16; ++k) {
            int j = g16 + 16 * k;
            rs += ls[j * 4 + comp]; rs2 += ls2[j * 4 + comp];
        }
        int slot = (t * G1 + blockIdx.x) * 64 + tid;
        PX[slot] = rs; PX2[slot] = rs2;
    }
}

// single atomic stream, runs alone: per-edge rank within dst bucket + deg
__global__ void k_rank(const int* __restrict__ dst, int* __restrict__ deg,
                       int* __restrict__ rank) {
    int e = blockIdx.x * 256 + threadIdx.x;
    if (e < EE) rank[e] = atomicAdd(&deg[dst[e]], 1);
}

// multi-block scan (3 small kernels — parallel, unlike the serial 1-block scan)
__global__ void k_scan1(const int* __restrict__ deg, int* __restrict__ bsum) {
    __shared__ int ls[256];
    int i = blockIdx.x * 256 + threadIdx.x;
    ls[threadIdx.x] = (i < NN) ? deg[i] : 0;
    __syncthreads();
    for (int off = 128; off > 0; off >>= 1) {
        if (threadIdx.x < off) ls[threadIdx.x] += ls[threadIdx.x + off];
        __syncthreads();
    }
    if (threadIdx.x == 0) bsum[blockIdx.x] = ls[0];
}

__global__ void k_scan2(const int* __restrict__ bsum, int* __restrict__ bscan) {
    __shared__ int ls[256];
    int tid = threadIdx.x;
    int v = (tid < NB) ? bsum[tid] : 0;
    ls[tid] = v;
    __syncthreads();
    for (int off = 1; off < 256; off <<= 1) {
        int t = (tid >= off) ? ls[tid - off] : 0;
        __syncthreads();
        ls[tid] += t;
        __syncthreads();
    }
    if (tid < NB) bscan[tid] = ls[tid] - v;   // exclusive
}

__global__ void k_scan3(const int* __restrict__ deg, const int* __restrict__ bscan,
                        int* __restrict__ row_start) {
    __shared__ int ls[256];
    int i = blockIdx.x * 256 + threadIdx.x;
    int tid = threadIdx.x;
    int v = (i < NN) ? deg[i] : 0;
    ls[tid] = v;
    __syncthreads();
    for (int off = 1; off < 256; off <<= 1) {
        int t = (tid >= off) ? ls[tid - off] : 0;
        __syncthreads();
        ls[tid] += t;
        __syncthreads();
    }
    int s = ls[tid] - v + bscan[blockIdx.x];  // exclusive prefix
    if (i < NN) row_start[i] = s;
    if (i == NN - 1) row_start[NN] = s + v;
}

// atomic-free CSR fill: position = row_start[dst] + rank
__global__ void k_fill2(const int* __restrict__ src, const int* __restrict__ dst,
                        const float* __restrict__ ew, const int* __restrict__ rank,
                        const int* __restrict__ row_start, int2* __restrict__ packed) {
    int e = blockIdx.x * 256 + threadIdx.x;
    if (e < EE) {
        int p = row_start[dst[e]] + rank[e];
        packed[p] = make_int2(src[e], __float_as_int(ew[e]));
    }
}

// one wave per node; lane l -> (t = l>>4, channels 4*(l&15)..+3), ushort4 gathers.
__global__ __launch_bounds__(256) void k_agg(
    const unsigned short* __restrict__ xb, const int2* __restrict__ packed,
    const int* __restrict__ row_start, unsigned short* __restrict__ avgb) {
    int wv = __builtin_amdgcn_readfirstlane(threadIdx.x >> 6);
    int n = blockIdx.x * 4 + wv;
    int l = threadIdx.x & 63;
    int t = l >> 4;
    int cg = (l & 15) * 4;
    const unsigned short* xt = xb + (size_t)t * NN * 64 + cg;
    int rs = row_start[n], re = row_start[n + 1];
    float a0 = 0.f, a1 = 0.f, a2 = 0.f, a3 = 0.f, wsum = 0.f;
    int e = rs;
    for (; e + 4 <= re; e += 4) {
        int2 p0 = packed[e], p1 = packed[e + 1], p2 = packed[e + 2], p3 = packed[e + 3];
        ushort4 v0 = *(const ushort4*)(xt + (size_t)p0.x * 64);
        ushort4 v1 = *(const ushort4*)(xt + (size_t)p1.x * 64);
        ushort4 v2 = *(const ushort4*)(xt + (size_t)p2.x * 64);
        ushort4 v3 = *(const ushort4*)(xt + (size_t)p3.x * 64);
        float w0 = __int_as_float(p0.y), w1 = __int_as_float(p1.y);
        float w2 = __int_as_float(p2.y), w3 = __int_as_float(p3.y);
        wsum += (w0 + w1) + (w2 + w3);
        a0 = fmaf(w0, b2f(v0.x), a0); a1 = fmaf(w0, b2f(v0.y), a1);
        a2 = fmaf(w0, b2f(v0.z), a2); a3 = fmaf(w0, b2f(v0.w), a3);
        a0 = fmaf(w1, b2f(v1.x), a0); a1 = fmaf(w1, b2f(v1.y), a1);
        a2 = fmaf(w1, b2f(v1.z), a2); a3 = fmaf(w1, b2f(v1.w), a3);
        a0 = fmaf(w2, b2f(v2.x), a0); a1 = fmaf(w2, b2f(v2.y), a1);
        a2 = fmaf(w2, b2f(v2.z), a2); a3 = fmaf(w2, b2f(v2.w), a3);
        a0 = fmaf(w3, b2f(v3.x), a0); a1 = fmaf(w3, b2f(v3.y), a1);
        a2 = fmaf(w3, b2f(v3.z), a2); a3 = fmaf(w3, b2f(v3.w), a3);
    }
    for (; e < re; ++e) {
        int2 p0 = packed[e];
        float w0 = __int_as_float(p0.y);
        ushort4 v0 = *(const ushort4*)(xt + (size_t)p0.x * 64);
        wsum += w0;
        a0 = fmaf(w0, b2f(v0.x), a0); a1 = fmaf(w0, b2f(v0.y), a1);
        a2 = fmaf(w0, b2f(v0.z), a2); a3 = fmaf(w0, b2f(v0.w), a3);
    }
    float rz = (wsum == 0.f) ? 1.f : (1.f / wsum);
    ushort4 o;
    o.x = f2b(a0 * rz); o.y = f2b(a1 * rz); o.z = f2b(a2 * rz); o.w = f2b(a3 * rz);
    *(ushort4*)(avgb + (size_t)t * NN * 64 + (size_t)n * 64 + cg) = o;
}

// per-c sum/sumsq partials of avg (bf16), short8 loads, no atomics
__global__ __launch_bounds__(256) void k_stats_avg(
    const unsigned short* __restrict__ avgb, float* __restrict__ PA,
    float* __restrict__ PA2) {
    int tid = threadIdx.x;
    int g = blockIdx.x * 256 + tid;
    const short8* av = (const short8*)avgb;
    float s[8], s2[8];
#pragma unroll
    for (int j = 0; j < 8; ++j) { s[j] = 0.f; s2[j] = 0.f; }
    for (int v = g; v < TT * NN * 8; v += G2 * 256) {
        short8 d = av[v];
#pragma unroll
        for (int j = 0; j < 8; ++j) {
            float f = b2f((unsigned short)d[j]);
            s[j] += f; s2[j] += f * f;
        }
    }
    __shared__ float ls[256 * 8], ls2[256 * 8];
#pragma unroll
    for (int j = 0; j < 8; ++j) { ls[tid * 8 + j] = s[j]; ls2[tid * 8 + j] = s2[j]; }
    __syncthreads();
    if (tid < 64) {
        int g8 = tid >> 3, comp = tid & 7;
        float rs = 0.f, rs2 = 0.f;
#pragma unroll
        for (int k = 0; k < 32; ++k) {
            int j = g8 + 8 * k;
            rs += ls[j * 8 + comp]; rs2 += ls2[j * 8 + comp];
        }
        PA[blockIdx.x * 64 + tid] = rs;
        PA2[blockIdx.x * 64 + tid] = rs2;
    }
}

// stage-2 reduce + BN fold into bf16 W1eff / fp32 b1eff
__global__ void k_fold(const float* __restrict__ W1, const float* __restrict__ b1,
                       const float* __restrict__ gamma, const float* __restrict__ beta,
                       const float* __restrict__ PX, const float* __restrict__ PX2,
                       const float* __restrict__ PA, const float* __restrict__ PA2,
                       unsigned short* __restrict__ W1eff, float* __restrict__ b1eff) {
    __shared__ float gS[192], hS[192];
    int c = threadIdx.x;                        // 192 threads
    const float inv = 1.0f / (float)(TT * NN);
    if (c < 192) {
        float s = 0.f, s2 = 0.f;
        if (c < 64) {
            for (int i = 0; i < TT * G1; ++i) { s += PX[i * 64 + c]; s2 += PX2[i * 64 + c]; }
        } else if (c < 128) {
            int cc = c - 64;                    // prev: t=0..2 only
            for (int i = 0; i < (TT - 1) * G1; ++i) { s += PX[i * 64 + cc]; s2 += PX2[i * 64 + cc]; }
        } else {
            int cc = c - 128;
            for (int i = 0; i < G2; ++i) { s += PA[i * 64 + cc]; s2 += PA2[i * 64 + cc]; }
        }
        float mu = s * inv, ex2 = s2 * inv;
        float var = ex2 - mu * mu;
        float g = gamma[c] / sqrtf(var + BN_EPS);
        gS[c] = g;
        hS[c] = beta[c] - mu * g;
    }
    __syncthreads();
    for (int i = threadIdx.x; i < 64 * 192; i += blockDim.x) {
        int cc = i % 192;
        W1eff[i] = f2b(W1[i] * gS[cc]);
    }
    if (threadIdx.x < 64) {
        int o = threadIdx.x;
        float acc = b1[o];
        for (int cc = 0; cc < 192; ++cc) acc += hS[cc] * W1[o * 192 + cc];
        b1eff[o] = acc;
    }
}

// MFMA GEMM: block = 4 waves, wave = 16 rows x 64 outs (4 col-tiles), K=192
__global__ __launch_bounds__(256) void k_main(
    const unsigned short* __restrict__ xb, const unsigned short* __restrict__ avgb,
    const unsigned short* __restrict__ Wb, const float* __restrict__ bias,
    float* __restrict__ out) {
    int wave = threadIdx.x >> 6;
    int lane = threadIdx.x & 63;
    int r0 = blockIdx.x * 64 + wave * 16;
    int m = lane & 15;
    int q = lane >> 4;

    const unsigned short* xrow = xb   + (size_t)(r0 + m) * 64 + q * 8;
    const unsigned short* prow = xb   + (size_t)(r0 - NN + m) * 64 + q * 8;
    const unsigned short* arow = avgb + (size_t)(r0 + m) * 64 + q * 8;
    bool has_prev = (r0 >= NN);

    floatx4 acc[4];
#pragma unroll
    for (int ct = 0; ct < 4; ++ct) acc[ct] = (floatx4){0.f, 0.f, 0.f, 0.f};

    const short8 zf = (short8){0, 0, 0, 0, 0, 0, 0, 0};

#pragma unroll
    for (int kc = 0; kc < 6; ++kc) {
        short8 a;
        if (kc < 2) {
            a = *(const short8*)(xrow + kc * 32);
        } else if (kc < 4) {
            a = has_prev ? *(const short8*)(prow + (kc - 2) * 32) : zf;
        } else {
            a = *(const short8*)(arow + (kc - 4) * 32);
        }
#pragma unroll
        for (int ct = 0; ct < 4; ++ct) {
            short8 b = *(const short8*)(Wb + (size_t)(ct * 16 + m) * 192 + kc * 32 + q * 8);
            acc[ct] = __builtin_amdgcn_mfma_f32_16x16x32_bf16(a, b, acc[ct], 0, 0, 0);
        }
    }

#pragma unroll
    for (int ct = 0; ct < 4; ++ct) {
        float bv = bias[ct * 16 + m];
#pragma unroll
        for (int i = 0; i < 4; ++i) {
            int row = q * 4 + i;
            out[(size_t)(r0 + row) * 64 + ct * 16 + m] = fmaxf(acc[ct][i] + bv, 0.f);
        }
    }
}

extern "C" void kernel_launch(void* const* d_in, const int* in_sizes, int n_in,
                              void* d_out, int out_size, void* d_ws, size_t ws_size,
                              hipStream_t stream) {
    const float* x     = (const float*)d_in[0];
    const float* ew    = (const float*)d_in[1];
    const float* W1    = (const float*)d_in[2];
    const float* b1    = (const float*)d_in[3];
    const float* gamma = (const float*)d_in[4];
    const float* beta  = (const float*)d_in[5];
    const int*   src   = (const int*)d_in[6];
    const int*   dst   = (const int*)d_in[7];
    float* out = (float*)d_out;
    char*  ws  = (char*)d_ws;

    int*   deg      = (int*)(ws + WS_DEG);
    int*   row_start= (int*)(ws + WS_ROWSTART);
    int*   bsum     = (int*)(ws + WS_BSUM);
    int*   bscan    = (int*)(ws + WS_BSCAN);
    float* PX       = (float*)(ws + WS_PX);
    float* PX2      = (float*)(ws + WS_PX2);
    float* PA       = (float*)(ws + WS_PA);
    float* PA2      = (float*)(ws + WS_PA2);
    unsigned short* W1eff = (unsigned short*)(ws + WS_W1EFF);
    float* b1eff    = (float*)(ws + WS_B1EFF);
    int2*  packed   = (int2*)(ws + WS_PACKED);
    unsigned short* xb   = (unsigned short*)(ws + WS_XB);
    unsigned short* avgb = (unsigned short*)(ws + WS_AVGB);
    int*   rank     = (int*)(ws + WS_RANK);

    hipMemsetAsync(ws, 0, 200000, stream);          // deg only

    k_rank<<<(EE + 255) / 256, 256, 0, stream>>>(dst, deg, rank);

    k_prep_stats<<<dim3(G1, TT), 256, 0, stream>>>(x, xb, PX, PX2);

    k_scan1<<<NB, 256, 0, stream>>>(deg, bsum);
    k_scan2<<<1, 256, 0, stream>>>(bsum, bscan);
    k_scan3<<<NB, 256, 0, stream>>>(deg, bscan, row_start);

    k_fill2<<<(EE + 255) / 256, 256, 0, stream>>>(src, dst, ew, rank, row_start, packed);

    k_agg<<<NN / 4, 256, 0, stream>>>(xb, packed, row_start, avgb);

    k_stats_avg<<<G2, 256, 0, stream>>>(avgb, PA, PA2);

    k_fold<<<1, 192, 0, stream>>>(W1, b1, gamma, beta, PX, PX2, PA, PA2, W1eff, b1eff);

    k_main<<<(TT * NN) / 64, 256, 0, stream>>>(xb, avgb, W1eff, b1eff, out);
}

// Round 9
// 333.727 us; speedup vs baseline: 1.1711x; 1.0574x over previous
//
#include <hip/hip_runtime.h>

#define TT 4
#define NN 50000
#define DH 64
#define EE 800000
#define BN_EPS 1e-5f
#define NB 196          // ceil(NN/256) scan blocks
#define G1 64           // prep blocks per t
#define G2 256          // blocks for stats_avg

typedef __attribute__((ext_vector_type(8))) short short8;
typedef __attribute__((ext_vector_type(4))) float floatx4;

// ---------------- ws layout (byte offsets) ----------------
#define WS_DEG      0          // 50000 i -> 200000
#define WS_FLAGS    200704     // 196 i (lookback flags) -> 201488
#define WS_ROWSTART 201728     // 50001 i -> 401732
#define WS_PX       401920     // [4][G1][64] f = 65536
#define WS_PX2      467456     // 65536
#define WS_PA       532992     // [G2][64] f = 65536
#define WS_PA2      598528     // 65536
#define WS_W1EFF    664064     // 12288 bf16 = 24576
#define WS_B1EFF    688640     // 64 f
#define WS_PACKED   1048576    // 800000 int2 = 6.4 MB
#define WS_XB       8388608    // 25.6 MB
#define WS_AVGB     34078720   // 25.6 MB -> ends 59678720
#define WS_RANK     34078720   // 800000 i (aliases avgb; dead before k_agg writes)

__device__ __forceinline__ unsigned short f2b(float f) {
    unsigned int u = __float_as_uint(f);
    unsigned int r = (u + 0x7FFFu + ((u >> 16) & 1u)) >> 16;
    return (unsigned short)r;
}
__device__ __forceinline__ float b2f(unsigned short u) {
    return __uint_as_float((unsigned int)u << 16);
}

// x(fp32, NT-load) -> xb(bf16) + per-(t,c) stats partials; also zeroes deg+flags
__global__ __launch_bounds__(256) void k_prep_stats(
    const float* __restrict__ x, unsigned short* __restrict__ xb,
    float* __restrict__ PX, float* __restrict__ PX2,
    int* __restrict__ deg, int* __restrict__ flags) {
    int t = blockIdx.y;
    int tid = threadIdx.x;
    int pb = t * G1 + blockIdx.x;              // 0..255
    int gid = pb * 256 + tid;                  // 0..65535
    if (gid < NN) deg[gid] = 0;
    else if (gid < NN + NB) flags[gid - NN] = 0;

    int g = blockIdx.x * 256 + tid;
    const floatx4* xt = (const floatx4*)(x + (size_t)t * NN * 64);
    unsigned short* xbt = xb + (size_t)t * NN * 64;
    float s[4] = {0.f, 0.f, 0.f, 0.f}, s2[4] = {0.f, 0.f, 0.f, 0.f};
    for (int v = g; v < NN * 16; v += G1 * 256) {     // stride mult of 16 -> c-group fixed
        floatx4 d = __builtin_nontemporal_load(&xt[v]); // x never re-read
        ushort4 o;
        o.x = f2b(d.x); o.y = f2b(d.y); o.z = f2b(d.z); o.w = f2b(d.w);
        *(ushort4*)(xbt + (size_t)v * 4) = o;
        s[0] += d.x; s2[0] += d.x * d.x;
        s[1] += d.y; s2[1] += d.y * d.y;
        s[2] += d.z; s2[2] += d.z * d.z;
        s[3] += d.w; s2[3] += d.w * d.w;
    }
    __shared__ float ls[256 * 4], ls2[256 * 4];
#pragma unroll
    for (int j = 0; j < 4; ++j) { ls[tid * 4 + j] = s[j]; ls2[tid * 4 + j] = s2[j]; }
    __syncthreads();
    if (tid < 64) {
        int g16 = tid >> 2, comp = tid & 3;
        float rs = 0.f, rs2 = 0.f;
#pragma unroll
        for (int k = 0; k < 16; ++k) {
            int j = g16 + 16 * k;
            rs += ls[j * 4 + comp]; rs2 += ls2[j * 4 + comp];
        }
        int slot = (t * G1 + blockIdx.x) * 64 + tid;
        PX[slot] = rs; PX2[slot] = rs2;
    }
}

// single atomic stream: per-edge rank within dst bucket + deg histogram
__global__ void k_rank(const int* __restrict__ dst, int* __restrict__ deg,
                       int* __restrict__ rank) {
    int e = blockIdx.x * 256 + threadIdx.x;
    if (e < EE) rank[e] = atomicAdd(&deg[dst[e]], 1);
}

// one-kernel exclusive scan via decoupled lookback.
// flags[b] = block b's aggregate + 1, published via atomicExch (value rides the atomic).
// Block b waits only on earlier blocks -> no deadlock regardless of residency.
__global__ __launch_bounds__(256) void k_scan_lb(
    const int* __restrict__ deg, int* __restrict__ flags,
    int* __restrict__ row_start) {
    int b = blockIdx.x, tid = threadIdx.x;
    int i = b * 256 + tid;
    int v = (i < NN) ? deg[i] : 0;
    __shared__ int ls[256];
    ls[tid] = v;
    __syncthreads();
    for (int off = 1; off < 256; off <<= 1) {
        int t = (tid >= off) ? ls[tid - off] : 0;
        __syncthreads();
        ls[tid] += t;
        __syncthreads();
    }
    int incl = ls[tid];
    if (tid == 0) atomicExch(&flags[b], ls[255] + 1);   // publish aggregate ASAP
    __shared__ int pre_s;
    if (tid == 0) pre_s = 0;
    __syncthreads();
    if (tid < b) {                                      // b <= 195 < 256: parallel poll
        int f;
        do { f = atomicAdd(&flags[tid], 0); } while (f == 0);
        atomicAdd(&pre_s, f - 1);
    }
    __syncthreads();
    int excl = pre_s + incl - v;
    if (i < NN) row_start[i] = excl;
    if (i == NN - 1) row_start[NN] = excl + v;
}

// atomic-free CSR fill: position = row_start[dst] + rank
__global__ void k_fill2(const int* __restrict__ src, const int* __restrict__ dst,
                        const float* __restrict__ ew, const int* __restrict__ rank,
                        const int* __restrict__ row_start, int2* __restrict__ packed) {
    int e = blockIdx.x * 256 + threadIdx.x;
    if (e < EE) {
        int p = row_start[dst[e]] + rank[e];
        packed[p] = make_int2(src[e], __float_as_int(ew[e]));
    }
}

// one wave per node; lane l -> (t = l>>4, channels 4*(l&15)..+3); 8-edge unroll.
__global__ __launch_bounds__(256) void k_agg(
    const unsigned short* __restrict__ xb, const int2* __restrict__ packed,
    const int* __restrict__ row_start, unsigned short* __restrict__ avgb) {
    int wv = __builtin_amdgcn_readfirstlane(threadIdx.x >> 6);
    int n = blockIdx.x * 4 + wv;
    int l = threadIdx.x & 63;
    int t = l >> 4;
    int cg = (l & 15) * 4;
    const unsigned short* xt = xb + (size_t)t * NN * 64 + cg;
    int rs = row_start[n], re = row_start[n + 1];
    float a0 = 0.f, a1 = 0.f, a2 = 0.f, a3 = 0.f, wsum = 0.f;
    int e = rs;
    for (; e + 8 <= re; e += 8) {
        int2 p[8];
        ushort4 v[8];
#pragma unroll
        for (int j = 0; j < 8; ++j) p[j] = packed[e + j];
#pragma unroll
        for (int j = 0; j < 8; ++j) v[j] = *(const ushort4*)(xt + (size_t)p[j].x * 64);
#pragma unroll
        for (int j = 0; j < 8; ++j) {
            float w = __int_as_float(p[j].y);
            wsum += w;
            a0 = fmaf(w, b2f(v[j].x), a0); a1 = fmaf(w, b2f(v[j].y), a1);
            a2 = fmaf(w, b2f(v[j].z), a2); a3 = fmaf(w, b2f(v[j].w), a3);
        }
    }
    for (; e < re; ++e) {
        int2 p0 = packed[e];
        float w0 = __int_as_float(p0.y);
        ushort4 v0 = *(const ushort4*)(xt + (size_t)p0.x * 64);
        wsum += w0;
        a0 = fmaf(w0, b2f(v0.x), a0); a1 = fmaf(w0, b2f(v0.y), a1);
        a2 = fmaf(w0, b2f(v0.z), a2); a3 = fmaf(w0, b2f(v0.w), a3);
    }
    float rz = (wsum == 0.f) ? 1.f : (1.f / wsum);
    ushort4 o;
    o.x = f2b(a0 * rz); o.y = f2b(a1 * rz); o.z = f2b(a2 * rz); o.w = f2b(a3 * rz);
    *(ushort4*)(avgb + (size_t)t * NN * 64 + (size_t)n * 64 + cg) = o;
}

// per-c sum/sumsq partials of avg (bf16), short8 loads, no atomics
__global__ __launch_bounds__(256) void k_stats_avg(
    const unsigned short* __restrict__ avgb, float* __restrict__ PA,
    float* __restrict__ PA2) {
    int tid = threadIdx.x;
    int g = blockIdx.x * 256 + tid;
    const short8* av = (const short8*)avgb;
    float s[8], s2[8];
#pragma unroll
    for (int j = 0; j < 8; ++j) { s[j] = 0.f; s2[j] = 0.f; }
    for (int v = g; v < TT * NN * 8; v += G2 * 256) {
        short8 d = av[v];
#pragma unroll
        for (int j = 0; j < 8; ++j) {
            float f = b2f((unsigned short)d[j]);
            s[j] += f; s2[j] += f * f;
        }
    }
    __shared__ float ls[256 * 8], ls2[256 * 8];
#pragma unroll
    for (int j = 0; j < 8; ++j) { ls[tid * 8 + j] = s[j]; ls2[tid * 8 + j] = s2[j]; }
    __syncthreads();
    if (tid < 64) {
        int g8 = tid >> 3, comp = tid & 7;
        float rs = 0.f, rs2 = 0.f;
#pragma unroll
        for (int k = 0; k < 32; ++k) {
            int j = g8 + 8 * k;
            rs += ls[j * 8 + comp]; rs2 += ls2[j * 8 + comp];
        }
        PA[blockIdx.x * 64 + tid] = rs;
        PA2[blockIdx.x * 64 + tid] = rs2;
    }
}

// stage-2 reduce + BN fold into bf16 W1eff / fp32 b1eff
__global__ void k_fold(const float* __restrict__ W1, const float* __restrict__ b1,
                       const float* __restrict__ gamma, const float* __restrict__ beta,
                       const float* __restrict__ PX, const float* __restrict__ PX2,
                       const float* __restrict__ PA, const float* __restrict__ PA2,
                       unsigned short* __restrict__ W1eff, float* __restrict__ b1eff) {
    __shared__ float gS[192], hS[192];
    int c = threadIdx.x;                        // 192 threads
    const float inv = 1.0f / (float)(TT * NN);
    if (c < 192) {
        float s = 0.f, s2 = 0.f;
        if (c < 64) {
            for (int i = 0; i < TT * G1; ++i) { s += PX[i * 64 + c]; s2 += PX2[i * 64 + c]; }
        } else if (c < 128) {
            int cc = c - 64;                    // prev: t=0..2 only
            for (int i = 0; i < (TT - 1) * G1; ++i) { s += PX[i * 64 + cc]; s2 += PX2[i * 64 + cc]; }
        } else {
            int cc = c - 128;
            for (int i = 0; i < G2; ++i) { s += PA[i * 64 + cc]; s2 += PA2[i * 64 + cc]; }
        }
        float mu = s * inv, ex2 = s2 * inv;
        float var = ex2 - mu * mu;
        float g = gamma[c] / sqrtf(var + BN_EPS);
        gS[c] = g;
        hS[c] = beta[c] - mu * g;
    }
    __syncthreads();
    for (int i = threadIdx.x; i < 64 * 192; i += blockDim.x) {
        int cc = i % 192;
        W1eff[i] = f2b(W1[i] * gS[cc]);
    }
    if (threadIdx.x < 64) {
        int o = threadIdx.x;
        float acc = b1[o];
        for (int cc = 0; cc < 192; ++cc) acc += hS[cc] * W1[o * 192 + cc];
        b1eff[o] = acc;
    }
}

// MFMA GEMM: block = 4 waves, wave = 16 rows x 64 outs (4 col-tiles), K=192
__global__ __launch_bounds__(256) void k_main(
    const unsigned short* __restrict__ xb, const unsigned short* __restrict__ avgb,
    const unsigned short* __restrict__ Wb, const float* __restrict__ bias,
    float* __restrict__ out) {
    int wave = threadIdx.x >> 6;
    int lane = threadIdx.x & 63;
    int r0 = blockIdx.x * 64 + wave * 16;
    int m = lane & 15;
    int q = lane >> 4;

    const unsigned short* xrow = xb   + (size_t)(r0 + m) * 64 + q * 8;
    const unsigned short* prow = xb   + (size_t)(r0 - NN + m) * 64 + q * 8;
    const unsigned short* arow = avgb + (size_t)(r0 + m) * 64 + q * 8;
    bool has_prev = (r0 >= NN);

    floatx4 acc[4];
#pragma unroll
    for (int ct = 0; ct < 4; ++ct) acc[ct] = (floatx4){0.f, 0.f, 0.f, 0.f};

    const short8 zf = (short8){0, 0, 0, 0, 0, 0, 0, 0};

#pragma unroll
    for (int kc = 0; kc < 6; ++kc) {
        short8 a;
        if (kc < 2) {
            a = *(const short8*)(xrow + kc * 32);
        } else if (kc < 4) {
            a = has_prev ? *(const short8*)(prow + (kc - 2) * 32) : zf;
        } else {
            a = *(const short8*)(arow + (kc - 4) * 32);
        }
#pragma unroll
        for (int ct = 0; ct < 4; ++ct) {
            short8 b = *(const short8*)(Wb + (size_t)(ct * 16 + m) * 192 + kc * 32 + q * 8);
            acc[ct] = __builtin_amdgcn_mfma_f32_16x16x32_bf16(a, b, acc[ct], 0, 0, 0);
        }
    }

#pragma unroll
    for (int ct = 0; ct < 4; ++ct) {
        float bv = bias[ct * 16 + m];
#pragma unroll
        for (int i = 0; i < 4; ++i) {
            int row = q * 4 + i;
            __builtin_nontemporal_store(fmaxf(acc[ct][i] + bv, 0.f),
                                        &out[(size_t)(r0 + row) * 64 + ct * 16 + m]);
        }
    }
}

extern "C" void kernel_launch(void* const* d_in, const int* in_sizes, int n_in,
                              void* d_out, int out_size, void* d_ws, size_t ws_size,
                              hipStream_t stream) {
    const float* x     = (const float*)d_in[0];
    const float* ew    = (const float*)d_in[1];
    const float* W1    = (const float*)d_in[2];
    const float* b1    = (const float*)d_in[3];
    const float* gamma = (const float*)d_in[4];
    const float* beta  = (const float*)d_in[5];
    const int*   src   = (const int*)d_in[6];
    const int*   dst   = (const int*)d_in[7];
    float* out = (float*)d_out;
    char*  ws  = (char*)d_ws;

    int*   deg      = (int*)(ws + WS_DEG);
    int*   flags    = (int*)(ws + WS_FLAGS);
    int*   row_start= (int*)(ws + WS_ROWSTART);
    float* PX       = (float*)(ws + WS_PX);
    float* PX2      = (float*)(ws + WS_PX2);
    float* PA       = (float*)(ws + WS_PA);
    float* PA2      = (float*)(ws + WS_PA2);
    unsigned short* W1eff = (unsigned short*)(ws + WS_W1EFF);
    float* b1eff    = (float*)(ws + WS_B1EFF);
    int2*  packed   = (int2*)(ws + WS_PACKED);
    unsigned short* xb   = (unsigned short*)(ws + WS_XB);
    unsigned short* avgb = (unsigned short*)(ws + WS_AVGB);
    int*   rank     = (int*)(ws + WS_RANK);

    k_prep_stats<<<dim3(G1, TT), 256, 0, stream>>>(x, xb, PX, PX2, deg, flags);

    k_rank<<<(EE + 255) / 256, 256, 0, stream>>>(dst, deg, rank);

    k_scan_lb<<<NB, 256, 0, stream>>>(deg, flags, row_start);

    k_fill2<<<(EE + 255) / 256, 256, 0, stream>>>(src, dst, ew, rank, row_start, packed);

    k_agg<<<NN / 4, 256, 0, stream>>>(xb, packed, row_start, avgb);

    k_stats_avg<<<G2, 256, 0, stream>>>(avgb, PA, PA2);

    k_fold<<<1, 192, 0, stream>>>(W1, b1, gamma, beta, PX, PX2, PA, PA2, W1eff, b1eff);

    k_main<<<(TT * NN) / 64, 256, 0, stream>>>(xb, avgb, W1eff, b1eff, out);
}